// Round 11
// baseline (36173.389 us; speedup 1.0000x reference)
//
#include <hip/hip_runtime.h>
#include <math.h>
#include <float.h>

// VQ-VAE VectorQuantizer forward, MI355X (gfx950). R11.
//   x: [16,4096,256] f32 (N=65536 rows), embedding: [4096,256] f32 (K=4096).
//   out: [0,16777216) quantized_st | [Q_OFF,+65536) indices(float) | [L_OFF] loss
//
// R10 post-mortem: all pipes idle (Mfma 9%/VALU 16%/HBM 9%) at 2 blocks/CU ->
// barrier-drain-bound (m233 signature). R11 = m97-proven occupancy config:
//  - BK 32: 16 KB/round, LDS ~34 KB -> 4 blocks/CU (16 waves) so co-resident
//    blocks hide each other's stage+drain (m97/m114 mechanism).
//  - candidate list moved to global scratch (CAP 12288/block) -> ovf
//    practically unreachable, LDS freed.
//  - seed pass dropped: update-then-collect from cold start only adds ~16
//    collects/row (per-lane first code), absorbed by CAP.
//  - numerics/fragment maps/rescore byte-identical to R10 (absmax 0.0).
//
// Exactness (R1/R5/R6/R10-proven): reference score bits =
// fl(xnorm - 2*serial_dot); AVX2-tree xnorm; ties -> lowest index via packed
// (key|idx) u64 atomicMin. Filter in dot space: collect d~ >= mu - Wd with
// per-lane running max mu <= true max (superset, order-independent);
// Wd = 0.018*||x||_blk*eM + 5e-5 >= 2E, E <= 2^-7*||x||*eM; exact fp32
// rescore decides. 16x16x32 A/B/C fragment maps HW-validated.
//
// Scratch inside out[0..16.7M) (overwritten by k_output at the end):
//   xb bf16 @0 | ebp bf16 @EB_OFF | xnorm @XN_OFF | emax2 @EMAX_OFF
//   glist u32 @LIST_OFF (512 blocks x 12288)

typedef unsigned int u32; typedef unsigned long long u64; typedef unsigned short u16;
typedef __attribute__((ext_vector_type(8))) short bf16x8;
typedef __attribute__((ext_vector_type(4))) float f32x4;

#define DIM      256
#define Q_OFF    16777216
#define L_OFF    16842752
#define EB_OFF   8388608
#define XN_OFF   8912896
#define EMAX_OFF 8978432
#define LIST_OFF 8978448
#define CAP6     12288

__device__ __forceinline__ u16 f2bf(float f) {           // RNE f32->bf16
    u32 u = __float_as_uint(f);
    return (u16)((u + 0x7FFFu + ((u >> 16) & 1u)) >> 16);
}
__device__ __forceinline__ u32 fkey(float f) {           // monotone f32->u32
    u32 u = __float_as_uint(f);
    return (u & 0x80000000u) ? ~u : (u | 0x80000000u);
}

// exact serial fmaf dot (R1-proven order) + packed atomicMin into LDS best
__device__ __forceinline__ void rescoreL(int lrow, int code,
                                         const float* __restrict__ xblk,
                                         const float* __restrict__ emb,
                                         const float* __restrict__ xnblk,
                                         u64* __restrict__ bestL) {
    const float4* xr = (const float4*)(xblk + (u32)lrow * DIM);
    const float4* er = (const float4*)(emb + (u32)code * DIM);
    float acc = 0.f;
    #pragma unroll 8
    for (int q = 0; q < 64; ++q) {
        float4 a = xr[q], b = er[q];
        acc = fmaf(a.x, b.x, acc); acc = fmaf(a.y, b.y, acc);
        acc = fmaf(a.z, b.z, acc); acc = fmaf(a.w, b.w, acc);
    }
    float sc = fmaf(-2.f, acc, xnblk[lrow]);
    atomicMin(&bestL[lrow], ((u64)fkey(sc) << 32) | (u32)code);
}

// ---------------------------------------------------------------------------
__global__ void k_init(float* __restrict__ out) {
    out[EMAX_OFF] = 0.f; out[L_OFF] = 0.f;
}

__global__ void k_conv(const float* __restrict__ x, u16* __restrict__ xb) {
    int g = blockIdx.x * 256 + threadIdx.x;              // 2,097,152 x 8 floats
    const float4* p = (const float4*)x + g * 2;
    float4 a = p[0], b = p[1];
    uint4 o;
    o.x = (u32)f2bf(a.x) | ((u32)f2bf(a.y) << 16);
    o.y = (u32)f2bf(a.z) | ((u32)f2bf(a.w) << 16);
    o.z = (u32)f2bf(b.x) | ((u32)f2bf(b.y) << 16);
    o.w = (u32)f2bf(b.z) | ((u32)f2bf(b.w) << 16);
    ((uint4*)xb)[g] = o;
}

// pack ebp[G][code][8] (G=k>>3) + per-code norm^2 -> atomicMax emax2
__global__ void k_packe(const float* __restrict__ e, u16* __restrict__ ebp,
                        float* __restrict__ out) {
    int tid = blockIdx.x * 256 + threadIdx.x;            // 131,072
    int c = tid >> 5, G = tid & 31;
    const float4* p = (const float4*)(e + c * DIM + G * 8);
    float4 a = p[0], b = p[1];
    uint4 o;
    o.x = (u32)f2bf(a.x) | ((u32)f2bf(a.y) << 16);
    o.y = (u32)f2bf(a.z) | ((u32)f2bf(a.w) << 16);
    o.z = (u32)f2bf(b.x) | ((u32)f2bf(b.y) << 16);
    o.w = (u32)f2bf(b.z) | ((u32)f2bf(b.w) << 16);
    *(uint4*)(ebp + (u32)(G * 4096 + c) * 8u) = o;
    float s8 = a.x*a.x + a.y*a.y + a.z*a.z + a.w*a.w
             + b.x*b.x + b.y*b.y + b.z*b.z + b.w*b.w;
    #pragma unroll
    for (int off = 1; off < 32; off <<= 1) s8 += __shfl_xor(s8, off, 64);
    if ((threadIdx.x & 31) == 0)
        atomicMax((int*)(out + EMAX_OFF), __float_as_int(s8));
}

// AVX2-tree row norm, 8 lanes/row (bit-identical to R1)
__global__ void k_prep(const float* __restrict__ x, float* __restrict__ out) {
    int g = blockIdx.x * 256 + threadIdx.x;              // 524,288
    int row = g >> 3, l = g & 7;
    const float* xr = x + row * DIM;
    float p = 0.f;
    #pragma unroll
    for (int i = 0; i < 32; ++i) { float v = xr[i*8 + l]; p = fmaf(v, v, p); }
    float q = p + __shfl_down(p, 4, 64);
    float r = q + __shfl_down(q, 2, 64);
    float s = r + __shfl_down(r, 1, 64);
    if (l == 0) out[XN_OFF + row] = s;
}

// ---------------------------------------------------------------------------
// Single-pass fused filter + rescore. 512 blocks x 256 thr (4 waves, 2x2 wave
// grid; wave = 64 rows x 64 cols). Block = 128 rows x all 4096 codes:
// 256 rounds of (CT = m>>3, KC = m&7); per round stage 8 A-frags + 8 B-frags
// (1 KB each, fragment-ordered, conflict-free) double-buffered; per wave
// K-step: 4+4 ds_read_b128 -> 16 MFMA (m97 ratio). Collect every 8th round.
// 4 blocks/CU (16 waves) hide the stage+drain latency (m97 occupancy).
// ---------------------------------------------------------------------------
__launch_bounds__(256, 4)
__global__ void k_vq6(const u16* __restrict__ xb, const u16* __restrict__ ebp,
                      const float* __restrict__ x, const float* __restrict__ emb,
                      const float* __restrict__ xnorm, const float* __restrict__ emax2,
                      u32* __restrict__ glist, float* __restrict__ idxf) {
    __shared__ u16 Aimg[2][4096];          // 2 x 8 KB
    __shared__ u16 Bimg[2][4096];          // 2 x 8 KB
    __shared__ u64 bestL[128];             // 1 KB
    __shared__ u32 cnt, ovf;
    __shared__ int xmax_bits;

    const int t = threadIdx.x, w = t >> 6, l = t & 63;
    const int l16 = l & 15, lhi = l >> 4;
    const int wr = w >> 1, wc = w & 1;
    const int brow = blockIdx.x * 128;
    u32* mylist = glist + (u32)blockIdx.x * CAP6;
    if (t == 0) { cnt = 0u; ovf = 0u; xmax_bits = 0; }
    if (t < 128) bestL[t] = ~0ULL;
    __syncthreads();
    if (t < 128) atomicMax(&xmax_bits, __float_as_int(xnorm[brow + t]));
    __syncthreads();
    const float Wd = 0.018f * sqrtf(__int_as_float(xmax_bits)) * sqrtf(emax2[0])
                   + 5.0e-5f;

    float md[16];
    #pragma unroll
    for (int s = 0; s < 16; ++s) md[s] = -FLT_MAX;
    f32x4 acc[4][4] = {};

    // ---- stage round (CT, KC): 8 A-frags + 8 B-frags of 1 KB; wave w does
    // frag pairs w*2, w*2+1. A-frag mf: lane -> xb[row=brow+mf*16+l16,
    // k=KC*32+lhi*8]. B-frag nf: lane -> ebp[G=KC*4+lhi, c=CT*128+nf*16+l16].
    #define STAGE(B, CT, KC) { \
        _Pragma("unroll") \
        for (int j_ = 0; j_ < 2; ++j_) { \
            const int f_ = w*2 + j_; \
            const u16* ga_ = xb + (u32)(brow + f_*16 + l16) * 256u \
                                + (u32)((KC)*32 + lhi*8); \
            __builtin_amdgcn_global_load_lds( \
                (const __attribute__((address_space(1))) u32*)ga_, \
                (__attribute__((address_space(3))) u32*)&Aimg[B][f_*512], 16, 0, 0); \
            const u16* gb_ = ebp + ((u32)((KC)*4 + lhi) * 4096u \
                                   + (u32)((CT)*128 + f_*16 + l16)) * 8u; \
            __builtin_amdgcn_global_load_lds( \
                (const __attribute__((address_space(1))) u32*)gb_, \
                (__attribute__((address_space(3))) u32*)&Bimg[B][f_*512], 16, 0, 0); \
        } }

    // ---- one K-step (32 dims): 4 A-reads + 4 B-reads -> 16 MFMA
    #define CHUNK_MFMA(B) { \
        bf16x8 a_[4], b_[4]; \
        _Pragma("unroll") \
        for (int i_ = 0; i_ < 4; ++i_) \
            a_[i_] = *(const bf16x8*)&Aimg[B][(wr*4 + i_)*512 + l*8]; \
        _Pragma("unroll") \
        for (int j_ = 0; j_ < 4; ++j_) \
            b_[j_] = *(const bf16x8*)&Bimg[B][(wc*4 + j_)*512 + l*8]; \
        _Pragma("unroll") \
        for (int i_ = 0; i_ < 4; ++i_) \
            _Pragma("unroll") \
            for (int j_ = 0; j_ < 4; ++j_) \
                acc[i_][j_] = __builtin_amdgcn_mfma_f32_16x16x32_bf16( \
                    a_[i_], b_[j_], acc[i_][j_], 0, 0, 0); \
    }

    #define MD_RESYNC { \
        _Pragma("unroll") \
        for (int s_ = 0; s_ < 16; ++s_) { \
            float v_ = md[s_]; \
            _Pragma("unroll") \
            for (int off_ = 1; off_ < 16; off_ <<= 1) \
                v_ = fmaxf(v_, __shfl_xor(v_, off_, 64)); \
            md[s_] = v_; \
        } }

    // ================ main: 256 rounds (CT=m>>3, KC=m&7) ================
    STAGE(0, 0, 0)
    __syncthreads();
    #pragma unroll 1
    for (int m = 0; m < 256; ++m) {
        const int buf = m & 1;
        if (m < 255) STAGE(buf ^ 1, (m+1) >> 3, (m+1) & 7)
        CHUNK_MFMA(buf)
        if ((m & 7) == 7) {
            const int ct = m >> 3;
            #pragma unroll
            for (int i = 0; i < 4; ++i)
                #pragma unroll
                for (int j = 0; j < 4; ++j)
                    #pragma unroll
                    for (int r = 0; r < 4; ++r) {
                        float v = acc[i][j][r];
                        float mu = fmaxf(md[i*4+r], v);
                        md[i*4+r] = mu;
                        if (v >= mu - Wd) {
                            u32 rl = (u32)(wr*64 + i*16 + lhi*4 + r);
                            u32 code = (u32)(ct*128 + (wc*4 + j)*16 + l16);
                            u32 pos = atomicAdd(&cnt, 1u);
                            if (pos < CAP6) mylist[pos] = (rl << 12) | code;
                            else ovf = 1u;
                        }
                        acc[i][j][r] = 0.f;
                    }
            if ((ct & 3) == 3) MD_RESYNC
        }
        __syncthreads();
    }

    // ================ exact rescore of candidates (block-local) ================
    const float* xblk = x + (u32)brow * DIM;
    const float* xnblk = xnorm + brow;
    if (ovf) {                               // practically unreachable safety net
        for (u32 p = (u32)t; p < 524288u; p += 256u)
            rescoreL((int)(p >> 12), (int)(p & 4095u), xblk, emb, xnblk, bestL);
    } else {
        u32 n = cnt;
        for (u32 i = (u32)t; i < n; i += 256u) {
            u32 e = mylist[i];
            rescoreL((int)(e >> 12), (int)(e & 4095u), xblk, emb, xnblk, bestL);
        }
    }
    __syncthreads();
    if (t < 128) idxf[brow + t] = (float)(u32)(bestL[t] & 0xFFFFFFFFu);
}

// ---------------------------------------------------------------------------
__global__ void k_output(const float* __restrict__ x, const float* __restrict__ emb,
                         const float* __restrict__ idx_f, float* __restrict__ out) {
    const int t = blockIdx.x * 256 + threadIdx.x;
    float lsum = 0.f;
    #pragma unroll
    for (int c = 0; c < 8; ++c) {
        int f4  = c * (2048*256) + t;
        int row = f4 >> 6;
        int c4  = f4 & 63;
        int idx = (int)idx_f[Q_OFF + row];
        float4 q  = ((const float4*)emb)[idx*64 + c4];
        float4 xv = ((const float4*)x)[f4];
        float4 o; float d;
        d = q.x - xv.x; o.x = xv.x + d; lsum = fmaf(d,d,lsum);
        d = q.y - xv.y; o.y = xv.y + d; lsum = fmaf(d,d,lsum);
        d = q.z - xv.z; o.z = xv.z + d; lsum = fmaf(d,d,lsum);
        d = q.w - xv.w; o.w = xv.w + d; lsum = fmaf(d,d,lsum);
        ((float4*)out)[f4] = o;
    }
    #pragma unroll
    for (int off = 32; off > 0; off >>= 1) lsum += __shfl_down(lsum, off, 64);
    __shared__ float wsum[4];
    if ((threadIdx.x & 63) == 0) wsum[threadIdx.x >> 6] = lsum;
    __syncthreads();
    if (threadIdx.x == 0)
        atomicAdd(&out[L_OFF], (wsum[0]+wsum[1]) + (wsum[2]+wsum[3]));
}

__global__ void k_final(float* __restrict__ out) {
    if (threadIdx.x == 0 && blockIdx.x == 0) {
        float m = out[L_OFF] * (1.f/16777216.f);
        out[L_OFF] = m + 0.25f * m;
    }
}

extern "C" void kernel_launch(void* const* d_in, const int* in_sizes, int n_in,
                              void* d_out, int out_size, void* d_ws, size_t ws_size,
                              hipStream_t stream) {
    const float* x   = (const float*)d_in[0];
    const float* emb = (const float*)d_in[1];
    float* out = (float*)d_out;
    u16* xb  = (u16*)out;
    u16* ebp = (u16*)(out + EB_OFF);
    u32* glist = (u32*)(out + LIST_OFF);

    hipLaunchKernelGGL(k_init,   dim3(1),    dim3(1),   0, stream, out);
    hipLaunchKernelGGL(k_conv,   dim3(8192), dim3(256), 0, stream, x, xb);
    hipLaunchKernelGGL(k_packe,  dim3(512),  dim3(256), 0, stream, emb, ebp, out);
    hipLaunchKernelGGL(k_prep,   dim3(2048), dim3(256), 0, stream, x, out);
    hipLaunchKernelGGL(k_vq6,    dim3(512),  dim3(256), 0, stream,
                       xb, ebp, x, emb, out + XN_OFF, out + EMAX_OFF,
                       glist, out + Q_OFF);
    hipLaunchKernelGGL(k_output, dim3(2048), dim3(256), 0, stream, x, emb, out, out);
    hipLaunchKernelGGL(k_final,  dim3(1),    dim3(1),   0, stream, out);
}

// Round 12
// 850.268 us; speedup vs baseline: 42.5435x; 42.5435x over previous
//
#include <hip/hip_runtime.h>
#include <math.h>
#include <float.h>

// VQ-VAE VectorQuantizer forward, MI355X (gfx950). R12.
//   x: [16,4096,256] f32 (N=65536 rows), embedding: [4096,256] f32 (K=4096).
//   out: [0,16777216) quantized_st | [Q_OFF,+65536) indices(float) | [L_OFF] loss
//
// R11 post-mortem: seed-pass removal made ovf DETERMINISTIC (16,384 first-
// evaluation collects/block > CAP) -> block-local brute fallback everywhere
// (36 ms; 2.5e8 LDS-atomic conflicts; MfmaUtil 0.15%). R12 restores a 2-tile
// seed pass (md = true row max over 256 codes before any collection, +6%
// MFMA) and raises CAP to 14336 (3x margin on ~4.6K expected cands/block).
// Structure otherwise identical to R11: BK=32, 16 KB/round fragment-ordered
// global_load_lds staging, double-buffered, 4 blocks/CU / 16 waves (m97
// occupancy so co-resident blocks hide stage+drain latency).
//
// Exactness (R1/R5/R6/R10-proven): reference score bits =
// fl(xnorm - 2*serial_dot); AVX2-tree xnorm; ties -> lowest index via packed
// (key|idx) u64 atomicMin. Filter in dot space: collect d~ >= mu - Wd with
// running max mu <= true max (superset, order-independent);
// Wd = 0.018*||x||_blk*eM + 5e-5 >= 2E, E <= 2^-7*||x||*eM; exact fp32
// rescore decides. 16x16x32 A/B/C fragment maps HW-validated (R10 no-ovf).
//
// Scratch inside out[0..16.7M) (overwritten by k_output at the end):
//   xb bf16 @0 | ebp bf16 @EB_OFF | xnorm @XN_OFF | emax2 @EMAX_OFF
//   glist u32 @LIST_OFF (512 blocks x 14336)

typedef unsigned int u32; typedef unsigned long long u64; typedef unsigned short u16;
typedef __attribute__((ext_vector_type(8))) short bf16x8;
typedef __attribute__((ext_vector_type(4))) float f32x4;

#define DIM      256
#define Q_OFF    16777216
#define L_OFF    16842752
#define EB_OFF   8388608
#define XN_OFF   8912896
#define EMAX_OFF 8978432
#define LIST_OFF 8978448
#define CAP6     14336

__device__ __forceinline__ u16 f2bf(float f) {           // RNE f32->bf16
    u32 u = __float_as_uint(f);
    return (u16)((u + 0x7FFFu + ((u >> 16) & 1u)) >> 16);
}
__device__ __forceinline__ u32 fkey(float f) {           // monotone f32->u32
    u32 u = __float_as_uint(f);
    return (u & 0x80000000u) ? ~u : (u | 0x80000000u);
}

// exact serial fmaf dot (R1-proven order) + packed atomicMin into LDS best
__device__ __forceinline__ void rescoreL(int lrow, int code,
                                         const float* __restrict__ xblk,
                                         const float* __restrict__ emb,
                                         const float* __restrict__ xnblk,
                                         u64* __restrict__ bestL) {
    const float4* xr = (const float4*)(xblk + (u32)lrow * DIM);
    const float4* er = (const float4*)(emb + (u32)code * DIM);
    float acc = 0.f;
    #pragma unroll 8
    for (int q = 0; q < 64; ++q) {
        float4 a = xr[q], b = er[q];
        acc = fmaf(a.x, b.x, acc); acc = fmaf(a.y, b.y, acc);
        acc = fmaf(a.z, b.z, acc); acc = fmaf(a.w, b.w, acc);
    }
    float sc = fmaf(-2.f, acc, xnblk[lrow]);
    atomicMin(&bestL[lrow], ((u64)fkey(sc) << 32) | (u32)code);
}

// ---------------------------------------------------------------------------
__global__ void k_init(float* __restrict__ out) {
    out[EMAX_OFF] = 0.f; out[L_OFF] = 0.f;
}

__global__ void k_conv(const float* __restrict__ x, u16* __restrict__ xb) {
    int g = blockIdx.x * 256 + threadIdx.x;              // 2,097,152 x 8 floats
    const float4* p = (const float4*)x + g * 2;
    float4 a = p[0], b = p[1];
    uint4 o;
    o.x = (u32)f2bf(a.x) | ((u32)f2bf(a.y) << 16);
    o.y = (u32)f2bf(a.z) | ((u32)f2bf(a.w) << 16);
    o.z = (u32)f2bf(b.x) | ((u32)f2bf(b.y) << 16);
    o.w = (u32)f2bf(b.z) | ((u32)f2bf(b.w) << 16);
    ((uint4*)xb)[g] = o;
}

// pack ebp[G][code][8] (G=k>>3) + per-code norm^2 -> atomicMax emax2
__global__ void k_packe(const float* __restrict__ e, u16* __restrict__ ebp,
                        float* __restrict__ out) {
    int tid = blockIdx.x * 256 + threadIdx.x;            // 131,072
    int c = tid >> 5, G = tid & 31;
    const float4* p = (const float4*)(e + c * DIM + G * 8);
    float4 a = p[0], b = p[1];
    uint4 o;
    o.x = (u32)f2bf(a.x) | ((u32)f2bf(a.y) << 16);
    o.y = (u32)f2bf(a.z) | ((u32)f2bf(a.w) << 16);
    o.z = (u32)f2bf(b.x) | ((u32)f2bf(b.y) << 16);
    o.w = (u32)f2bf(b.z) | ((u32)f2bf(b.w) << 16);
    *(uint4*)(ebp + (u32)(G * 4096 + c) * 8u) = o;
    float s8 = a.x*a.x + a.y*a.y + a.z*a.z + a.w*a.w
             + b.x*b.x + b.y*b.y + b.z*b.z + b.w*b.w;
    #pragma unroll
    for (int off = 1; off < 32; off <<= 1) s8 += __shfl_xor(s8, off, 64);
    if ((threadIdx.x & 31) == 0)
        atomicMax((int*)(out + EMAX_OFF), __float_as_int(s8));
}

// AVX2-tree row norm, 8 lanes/row (bit-identical to R1)
__global__ void k_prep(const float* __restrict__ x, float* __restrict__ out) {
    int g = blockIdx.x * 256 + threadIdx.x;              // 524,288
    int row = g >> 3, l = g & 7;
    const float* xr = x + row * DIM;
    float p = 0.f;
    #pragma unroll
    for (int i = 0; i < 32; ++i) { float v = xr[i*8 + l]; p = fmaf(v, v, p); }
    float q = p + __shfl_down(p, 4, 64);
    float r = q + __shfl_down(q, 2, 64);
    float s = r + __shfl_down(r, 1, 64);
    if (l == 0) out[XN_OFF + row] = s;
}

// ---------------------------------------------------------------------------
// Single-pass fused filter + rescore. 512 blocks x 256 thr (4 waves, 2x2 wave
// grid; wave = 64 rows x 64 cols). Block = 128 rows x all 4096 codes.
// Seed: 16 rounds over CT 0..1 (256 codes), md only. Main: 256 rounds
// (CT = m>>3, KC = m&7); per round stage 8 A-frags + 8 B-frags (1 KB each,
// fragment-ordered, conflict-free) double-buffered; per wave K-step: 4+4
// ds_read_b128 -> 16 MFMA (m97 ratio). Collect every 8th round vs seeded md.
// ---------------------------------------------------------------------------
__launch_bounds__(256, 4)
__global__ void k_vq6(const u16* __restrict__ xb, const u16* __restrict__ ebp,
                      const float* __restrict__ x, const float* __restrict__ emb,
                      const float* __restrict__ xnorm, const float* __restrict__ emax2,
                      u32* __restrict__ glist, float* __restrict__ idxf) {
    __shared__ u16 Aimg[2][4096];          // 2 x 8 KB
    __shared__ u16 Bimg[2][4096];          // 2 x 8 KB
    __shared__ u64 bestL[128];             // 1 KB
    __shared__ u32 cnt, ovf;
    __shared__ int xmax_bits;

    const int t = threadIdx.x, w = t >> 6, l = t & 63;
    const int l16 = l & 15, lhi = l >> 4;
    const int wr = w >> 1, wc = w & 1;
    const int brow = blockIdx.x * 128;
    u32* mylist = glist + (u32)blockIdx.x * CAP6;
    if (t == 0) { cnt = 0u; ovf = 0u; xmax_bits = 0; }
    if (t < 128) bestL[t] = ~0ULL;
    __syncthreads();
    if (t < 128) atomicMax(&xmax_bits, __float_as_int(xnorm[brow + t]));
    __syncthreads();
    const float Wd = 0.018f * sqrtf(__int_as_float(xmax_bits)) * sqrtf(emax2[0])
                   + 5.0e-5f;

    float md[16];
    #pragma unroll
    for (int s = 0; s < 16; ++s) md[s] = -FLT_MAX;
    f32x4 acc[4][4] = {};

    // ---- stage round (CT, KC): 8 A-frags + 8 B-frags of 1 KB; wave w does
    // frag pairs w*2, w*2+1. A-frag mf: lane -> xb[row=brow+mf*16+l16,
    // k=KC*32+lhi*8]. B-frag nf: lane -> ebp[G=KC*4+lhi, c=CT*128+nf*16+l16].
    #define STAGE(B, CT, KC) { \
        _Pragma("unroll") \
        for (int j_ = 0; j_ < 2; ++j_) { \
            const int f_ = w*2 + j_; \
            const u16* ga_ = xb + (u32)(brow + f_*16 + l16) * 256u \
                                + (u32)((KC)*32 + lhi*8); \
            __builtin_amdgcn_global_load_lds( \
                (const __attribute__((address_space(1))) u32*)ga_, \
                (__attribute__((address_space(3))) u32*)&Aimg[B][f_*512], 16, 0, 0); \
            const u16* gb_ = ebp + ((u32)((KC)*4 + lhi) * 4096u \
                                   + (u32)((CT)*128 + f_*16 + l16)) * 8u; \
            __builtin_amdgcn_global_load_lds( \
                (const __attribute__((address_space(1))) u32*)gb_, \
                (__attribute__((address_space(3))) u32*)&Bimg[B][f_*512], 16, 0, 0); \
        } }

    // ---- one K-step (32 dims): 4 A-reads + 4 B-reads -> 16 MFMA
    #define CHUNK_MFMA(B) { \
        bf16x8 a_[4], b_[4]; \
        _Pragma("unroll") \
        for (int i_ = 0; i_ < 4; ++i_) \
            a_[i_] = *(const bf16x8*)&Aimg[B][(wr*4 + i_)*512 + l*8]; \
        _Pragma("unroll") \
        for (int j_ = 0; j_ < 4; ++j_) \
            b_[j_] = *(const bf16x8*)&Bimg[B][(wc*4 + j_)*512 + l*8]; \
        _Pragma("unroll") \
        for (int i_ = 0; i_ < 4; ++i_) \
            _Pragma("unroll") \
            for (int j_ = 0; j_ < 4; ++j_) \
                acc[i_][j_] = __builtin_amdgcn_mfma_f32_16x16x32_bf16( \
                    a_[i_], b_[j_], acc[i_][j_], 0, 0, 0); \
    }

    #define MD_RESYNC { \
        _Pragma("unroll") \
        for (int s_ = 0; s_ < 16; ++s_) { \
            float v_ = md[s_]; \
            _Pragma("unroll") \
            for (int off_ = 1; off_ < 16; off_ <<= 1) \
                v_ = fmaxf(v_, __shfl_xor(v_, off_, 64)); \
            md[s_] = v_; \
        } }

    // ================ seed: 16 rounds, CT 0..1 (256 codes), md only ===========
    STAGE(0, 0, 0)
    __syncthreads();
    #pragma unroll 1
    for (int m = 0; m < 16; ++m) {
        const int buf = m & 1;
        if (m < 15) STAGE(buf ^ 1, (m+1) >> 3, (m+1) & 7)
        CHUNK_MFMA(buf)
        if ((m & 7) == 7) {
            #pragma unroll
            for (int i = 0; i < 4; ++i)
                #pragma unroll
                for (int j = 0; j < 4; ++j)
                    #pragma unroll
                    for (int r = 0; r < 4; ++r) {
                        md[i*4+r] = fmaxf(md[i*4+r], acc[i][j][r]);
                        acc[i][j][r] = 0.f;
                    }
        }
        __syncthreads();
    }
    MD_RESYNC   // md = true row max over seed codes -> no first-eval collects

    // ================ main: 256 rounds (CT=m>>3, KC=m&7) ================
    STAGE(0, 0, 0)
    __syncthreads();
    #pragma unroll 1
    for (int m = 0; m < 256; ++m) {
        const int buf = m & 1;
        if (m < 255) STAGE(buf ^ 1, (m+1) >> 3, (m+1) & 7)
        CHUNK_MFMA(buf)
        if ((m & 7) == 7) {
            const int ct = m >> 3;
            #pragma unroll
            for (int i = 0; i < 4; ++i)
                #pragma unroll
                for (int j = 0; j < 4; ++j)
                    #pragma unroll
                    for (int r = 0; r < 4; ++r) {
                        float v = acc[i][j][r];
                        float mu = fmaxf(md[i*4+r], v);
                        md[i*4+r] = mu;
                        if (v >= mu - Wd) {
                            u32 rl = (u32)(wr*64 + i*16 + lhi*4 + r);
                            u32 code = (u32)(ct*128 + (wc*4 + j)*16 + l16);
                            u32 pos = atomicAdd(&cnt, 1u);
                            if (pos < CAP6) mylist[pos] = (rl << 12) | code;
                            else ovf = 1u;
                        }
                        acc[i][j][r] = 0.f;
                    }
            if ((ct & 3) == 3) MD_RESYNC
        }
        __syncthreads();
    }

    // ================ exact rescore of candidates (block-local) ================
    const float* xblk = x + (u32)brow * DIM;
    const float* xnblk = xnorm + brow;
    if (ovf) {                               // safety net (3x CAP margin)
        for (u32 p = (u32)t; p < 524288u; p += 256u)
            rescoreL((int)(p >> 12), (int)(p & 4095u), xblk, emb, xnblk, bestL);
    } else {
        u32 n = cnt;
        for (u32 i = (u32)t; i < n; i += 256u) {
            u32 e = mylist[i];
            rescoreL((int)(e >> 12), (int)(e & 4095u), xblk, emb, xnblk, bestL);
        }
    }
    __syncthreads();
    if (t < 128) idxf[brow + t] = (float)(u32)(bestL[t] & 0xFFFFFFFFu);
}

// ---------------------------------------------------------------------------
__global__ void k_output(const float* __restrict__ x, const float* __restrict__ emb,
                         const float* __restrict__ idx_f, float* __restrict__ out) {
    const int t = blockIdx.x * 256 + threadIdx.x;
    float lsum = 0.f;
    #pragma unroll
    for (int c = 0; c < 8; ++c) {
        int f4  = c * (2048*256) + t;
        int row = f4 >> 6;
        int c4  = f4 & 63;
        int idx = (int)idx_f[Q_OFF + row];
        float4 q  = ((const float4*)emb)[idx*64 + c4];
        float4 xv = ((const float4*)x)[f4];
        float4 o; float d;
        d = q.x - xv.x; o.x = xv.x + d; lsum = fmaf(d,d,lsum);
        d = q.y - xv.y; o.y = xv.y + d; lsum = fmaf(d,d,lsum);
        d = q.z - xv.z; o.z = xv.z + d; lsum = fmaf(d,d,lsum);
        d = q.w - xv.w; o.w = xv.w + d; lsum = fmaf(d,d,lsum);
        ((float4*)out)[f4] = o;
    }
    #pragma unroll
    for (int off = 32; off > 0; off >>= 1) lsum += __shfl_down(lsum, off, 64);
    __shared__ float wsum[4];
    if ((threadIdx.x & 63) == 0) wsum[threadIdx.x >> 6] = lsum;
    __syncthreads();
    if (threadIdx.x == 0)
        atomicAdd(&out[L_OFF], (wsum[0]+wsum[1]) + (wsum[2]+wsum[3]));
}

__global__ void k_final(float* __restrict__ out) {
    if (threadIdx.x == 0 && blockIdx.x == 0) {
        float m = out[L_OFF] * (1.f/16777216.f);
        out[L_OFF] = m + 0.25f * m;
    }
}

extern "C" void kernel_launch(void* const* d_in, const int* in_sizes, int n_in,
                              void* d_out, int out_size, void* d_ws, size_t ws_size,
                              hipStream_t stream) {
    const float* x   = (const float*)d_in[0];
    const float* emb = (const float*)d_in[1];
    float* out = (float*)d_out;
    u16* xb  = (u16*)out;
    u16* ebp = (u16*)(out + EB_OFF);
    u32* glist = (u32*)(out + LIST_OFF);

    hipLaunchKernelGGL(k_init,   dim3(1),    dim3(1),   0, stream, out);
    hipLaunchKernelGGL(k_conv,   dim3(8192), dim3(256), 0, stream, x, xb);
    hipLaunchKernelGGL(k_packe,  dim3(512),  dim3(256), 0, stream, emb, ebp, out);
    hipLaunchKernelGGL(k_prep,   dim3(2048), dim3(256), 0, stream, x, out);
    hipLaunchKernelGGL(k_vq6,    dim3(512),  dim3(256), 0, stream,
                       xb, ebp, x, emb, out + XN_OFF, out + EMAX_OFF,
                       glist, out + Q_OFF);
    hipLaunchKernelGGL(k_output, dim3(2048), dim3(256), 0, stream, x, emb, out, out);
    hipLaunchKernelGGL(k_final,  dim3(1),    dim3(1),   0, stream, out);
}